// Round 2
// baseline (84.203 us; speedup 1.0000x reference)
//
#include <hip/hip_runtime.h>

#define Bb   8
#define Nn   4096
#define Hh   11
#define Wdd  176
#define HW   (Hh * Wdd)      // 1936
#define CIN  72
#define COUT 18
#define WINN 5
#define NCELL (Bb * HW)                      // 15488
#define NBOX  (Bb * Nn)                      // 32768
#define M_PER_B (Nn * WINN * WINN * 6)       // 614400
#define C6LN4 8.317766166719343f             // 6 * ln(4), invalid-sample CE

// Kernel 1: fused 1x1 conv (72->18) + 6x 4-class CE per spatial cell.
// One thread per (b, hw). Weights read via wave-uniform addresses -> compiler
// emits s_load into SGPRs (no LDS, no ds_read serialization, no barrier).
// Block 0 wave 0 also zeroes the output buffer (replaces the memset node).
__global__ __launch_bounds__(256) void conv_ce_kernel(
    const float* __restrict__ feat,   // [B,72,HW]
    const float* __restrict__ labels, // [B,6,HW]
    const float* __restrict__ Wc,     // [18,72]
    const float* __restrict__ bc,     // [18]
    float* __restrict__ cesum,        // [B*HW]
    float* __restrict__ out,          // [out_n]
    int out_n)
{
    if (blockIdx.x == 0) {
        for (int i = threadIdx.x; i < out_n; i += 256) out[i] = 0.0f;
    }

    int tid = blockIdx.x * 256 + threadIdx.x;
    if (tid >= NCELL) return;
    int hw = tid % HW;
    int b  = tid / HW;

    const float* fb = feat + (size_t)b * CIN * HW + hw;
    float acc[COUT];
#pragma unroll
    for (int o = 0; o < COUT; ++o) acc[o] = bc[o];   // uniform -> s_load

#pragma unroll 4
    for (int c = 0; c < CIN; ++c) {
        float f = fb[(size_t)c * HW];      // coalesced across lanes (consecutive hw)
#pragma unroll
        for (int o = 0; o < COUT; ++o)
            acc[o] = fmaf(f, Wc[o * CIN + c], acc[o]);   // Wc: wave-uniform -> SGPR operand
    }

    const float* gb = labels + (size_t)b * 6 * HW + hw;
    float s = 0.0f;
#pragma unroll
    for (int g = 0; g < 6; ++g) {
        float f0 = acc[3 * g + 0], f1 = acc[3 * g + 1], f2 = acc[3 * g + 2];
        int t = (int)gb[(size_t)g * HW];   // labels in {0..3}, nonneg
        float m = fmaxf(fmaxf(f0, f1), fmaxf(f2, 0.0f));
        float sum = __expf(0.0f - m) + __expf(f0 - m) + __expf(f1 - m) + __expf(f2 - m);
        float lse = m + __logf(sum);
        float lt = (t == 0) ? 0.0f : ((t == 1) ? f0 : ((t == 2) ? f1 : f2));
        s += lse - lt;
    }
    cesum[tid] = s;
}

// Kernel 2: one thread per box. Box math once, 25 single-float gathers of the
// per-cell CE table (62 KB total, 7.7 KB per batch -> L1-resident),
// invalid -> constant 6*ln4.
__global__ __launch_bounds__(256) void box_ce_reduce_kernel(
    const float* __restrict__ rois,   // [B,N,7]
    const float* __restrict__ cesum,  // [B*HW]
    float* __restrict__ out)          // [1]
{
    int tid = blockIdx.x * 256 + threadIdx.x;   // 0..NBOX-1 (exact grid)
    float local = 0.0f;

    int b = tid >> 12;                          // tid / 4096
    const float* r = rois + (size_t)tid * 7;
    float x0 = r[0], z0 = r[2], dx = r[3], dy = r[4], dz = r[5], th = r[6];
    float half = (dy * cosf(th) + dx * sinf(th)) * 0.5f;
    float x1 = x0 - half, x2 = x0 + half;
    float z1 = z0 - dz * 0.5f, z2 = z0 + dz * 0.5f;

    int   iw[5], ih[5];
    bool  vw[5], vh[5];
#pragma unroll
    for (int k = 0; k < 5; ++k) {
        float t = (float)k * 0.25f;
        float gz  = z1 + (z2 - z1) * t;
        float gzn = (gz - 1.0f) * 0.25f;
        int w = (int)rintf((gzn + 1.0f) * 0.5f * (float)(Wdd - 1));
        vw[k] = (w >= 0) && (w < Wdd);
        iw[k] = min(max(w, 0), Wdd - 1);
        float gx  = x1 + (x2 - x1) * t;
        float gxn = (gx - 35.2f) / 70.4f;
        int h = (int)rintf((gxn + 1.0f) * 0.5f * (float)(Hh - 1));
        vh[k] = (h >= 0) && (h < Hh);
        ih[k] = min(max(h, 0), Hh - 1);
    }

    const float* cb = cesum + (size_t)b * HW;
#pragma unroll
    for (int j = 0; j < 5; ++j) {
#pragma unroll
        for (int i = 0; i < 5; ++i) {
            local += (vh[j] && vw[i]) ? cb[ih[j] * Wdd + iw[i]] : C6LN4;
        }
    }

    // wave (64-lane) + block reduction, one atomic per block
    for (int off = 32; off > 0; off >>= 1)
        local += __shfl_down(local, off, 64);
    __shared__ float wsum[4];
    int lane = threadIdx.x & 63;
    int wid  = threadIdx.x >> 6;
    if (lane == 0) wsum[wid] = local;
    __syncthreads();
    if (threadIdx.x == 0) {
        float s = wsum[0] + wsum[1] + wsum[2] + wsum[3];
        atomicAdd(out, s * (1.0f / (float)M_PER_B));
    }
}

extern "C" void kernel_launch(void* const* d_in, const int* in_sizes, int n_in,
                              void* d_out, int out_size, void* d_ws, size_t ws_size,
                              hipStream_t stream) {
    const float* rois   = (const float*)d_in[0];  // [8,4096,7]
    const float* feat   = (const float*)d_in[1];  // [8,72,11,176]
    const float* labels = (const float*)d_in[2];  // [8,6*11*176]
    const float* Wc     = (const float*)d_in[3];  // [18,72]
    const float* bc     = (const float*)d_in[4];  // [18]
    float* out   = (float*)d_out;                 // [out_size]
    float* cesum = (float*)d_ws;                  // [15488] = 62 KB

    // out is zeroed by conv_ce_kernel block 0 (same-stream ordering makes it
    // visible to box_ce_reduce_kernel's atomics) -> no memset dispatch needed.
    conv_ce_kernel<<<(NCELL + 255) / 256, 256, 0, stream>>>(feat, labels, Wc, bc, cesum, out, out_size);
    box_ce_reduce_kernel<<<NBOX / 256, 256, 0, stream>>>(rois, cesum, out);
}